// Round 1
// baseline (607.034 us; speedup 1.0000x reference)
//
#include <hip/hip_runtime.h>
#include <cstdint>
#include <cstddef>

// Problem constants: B=128, L=64, F=3072, D=1024, CV=512, CN=1024, MAX_K=8
typedef unsigned short u16;
typedef __attribute__((ext_vector_type(8))) short short8;   // 8 x bf16 (4 VGPRs)
typedef __attribute__((ext_vector_type(4))) float f32x4;    // MFMA accumulator

static __device__ __forceinline__ float bf2f(u16 h) {
  union { unsigned u; float f; } a; a.u = ((unsigned)h) << 16; return a.f;
}
static __device__ __forceinline__ u16 f2bf(float x) {
  union { float f; unsigned u; } a; a.f = x;
  return (u16)((a.u + 0x7fffu + ((a.u >> 16) & 1u)) >> 16);  // RNE
}

// async global->LDS, 16B per lane. LDS dest must be wave-uniform base + lane*16,
// which our chunk = linear-thread-id mapping guarantees.
#define GLDS16(gp, lp)                                                          \
  __builtin_amdgcn_global_load_lds(                                             \
      (const __attribute__((address_space(1))) void*)(gp),                      \
      (__attribute__((address_space(3))) void*)(lp), 16, 0, 0)

// ---------------------------------------------------------------- prep kernels

// fp32 -> bf16 cast, vectorized (float4 in, 4x bf16 out)
__global__ void cast_inputs(const float4* __restrict__ in, ushort4* __restrict__ out, int n4) {
  int i = blockIdx.x * 256 + threadIdx.x;
  if (i < n4) {
    float4 v = in[i];
    ushort4 o;
    o.x = f2bf(v.x); o.y = f2bf(v.y); o.z = f2bf(v.z); o.w = f2bf(v.w);
    out[i] = o;
  }
}

// Wt[j][k] = W_{j>>10}[k][j&1023] as bf16   (j in [0,3072): concat cols of W0|W1|W2)
__global__ void transpose_w(const float* __restrict__ W0, const float* __restrict__ W1,
                            const float* __restrict__ W2, u16* __restrict__ Wt) {
  __shared__ float tile[32][33];
  const int tx = threadIdx.x, ty = threadIdx.y;   // block (32,8)
  const int kb = blockIdx.x * 32;                 // k block  [0,3072)
  const int jb = blockIdx.y * 32;                 // j block  [0,3072)
  const int w = jb >> 10;
  const float* W = (w == 0) ? W0 : ((w == 1) ? W1 : W2);
  const int nb = jb & 1023;
  for (int i = ty; i < 32; i += 8)
    tile[i][tx] = W[(size_t)(kb + i) * 1024 + nb + tx];
  __syncthreads();
  for (int i = ty; i < 32; i += 8)
    Wt[(size_t)(jb + i) * 3072 + kb + tx] = f2bf(tile[tx][i]);
}

// KVt[c][t*1024+d] = Kv[c][d][t] * bn_scale(c); biasv[c] = (bv-mean)*scale+beta
__global__ void prep_kv(const float* __restrict__ Kv, const float* __restrict__ bv,
                        const float* __restrict__ g, const float* __restrict__ beta,
                        const float* __restrict__ mean, const float* __restrict__ var,
                        u16* __restrict__ KVt, float* __restrict__ biasv) {
  const int c = blockIdx.x;
  const int tid = threadIdx.x;
  const float scale = g[c] * rsqrtf(var[c] + 1e-5f);
  for (int t = 0; t < 3; t++)
    for (int d = tid; d < 1024; d += 256)
      KVt[(size_t)c * 3072 + t * 1024 + d] = f2bf(Kv[(size_t)c * 3072 + d * 3 + t] * scale);
  if (tid == 0) biasv[c] = (bv[c] - mean[c]) * scale + beta[c];
}

__global__ void prep_kn(const float* __restrict__ Kn, const float* __restrict__ bnb,
                        const float* __restrict__ g, const float* __restrict__ beta,
                        const float* __restrict__ mean, const float* __restrict__ var,
                        u16* __restrict__ KNt, float* __restrict__ biasn) {
  const int c = blockIdx.x;
  const int tid = threadIdx.x;
  const float scale = g[c] * rsqrtf(var[c] + 1e-5f);
  for (int d = tid; d < 1024; d += 256)
    KNt[(size_t)c * 1024 + d] = f2bf(Kn[(size_t)c * 1024 + d] * scale);
  if (tid == 0) biasn[c] = (bnb[c] - mean[c]) * scale + beta[c];
}

// zero rows 0 and 65 of e1pad (B,66,D) — ws is re-poisoned every launch
__global__ void zero_pad(u16* __restrict__ e1pad) {
  const int i = blockIdx.x * 256 + threadIdx.x;  // 0..262143
  const int b = i >> 11;
  const int j = i & 2047;
  const int r = (j < 1024) ? 0 : 65;
  const int d = j & 1023;
  e1pad[(size_t)(b * 66 + r) * 1024 + d] = 0;
}

// ------------------------------------------------------------------ GEMM tile
// 128x128 C-tile, BK=32, 256 threads = 4 waves in 2x2 grid, each wave 64x64 via
// 4x4 mfma_f32_16x16x32_bf16. A row-major (M,K); B stored N-major (Bmat[n][k]).
// MODE 0: embed GEMM, K=3072, N=3072 ([W0|W1|W2]); epilogue: +bias, write
//         e0->bf16 ws, e1->fp32 out + bf16 e1pad(row l+1), e2->fp32 out + bf16 ws
// MODE 1: verb conv GEMM, A=e1pad im2col (t = k/1024 row shift), N=512,
//         epilogue: +biasv, sigmoid -> logits bf16
// MODE 2: noun conv GEMM, A=e2bf, K=1024, N=1024, sigmoid -> logits bf16
template<int MODE>
__global__ void gemm_tile(const u16* __restrict__ A, const u16* __restrict__ Bmat,
                          const float* __restrict__ bias0, const float* __restrict__ bias1,
                          const float* __restrict__ bias2,
                          float* __restrict__ oute1, float* __restrict__ oute2,
                          u16* __restrict__ e0bf, u16* __restrict__ e1pad,
                          u16* __restrict__ e2bf, u16* __restrict__ logits) {
  constexpr int K   = (MODE == 2) ? 1024 : 3072;
  constexpr int ldA = (MODE == 0) ? 3072 : 1024;
  constexpr int ldB = (MODE == 2) ? 1024 : 3072;
  constexpr int NC  = (MODE == 1) ? 512 : 1024;

  __shared__ __align__(16) u16 As[128 * 32];
  __shared__ __align__(16) u16 Bs[128 * 32];

  const int tid = threadIdx.x;
  const int m0 = blockIdx.y * 128;
  const int n0 = blockIdx.x * 128;

  // staging: chunk s in {tid, tid+256}; row = s>>2 (0..127), k-sub = (s&3)*8
  const int srow = tid >> 2;        // 0..63 (chunk tid); chunk tid+256 -> row 64+srow
  const int sq   = (tid & 3) * 8;

  const u16* aR0 = A;
  const u16* aR1 = A;
  int rb0 = 0, rb1 = 0;
  if constexpr (MODE == 1) {
    const int bb = m0 >> 6;                    // rows 0..63 -> batch bb, 64..127 -> bb+1
    rb0 = (bb * 66 + srow) * 1024;             // l = srow; +t*1024 added per k-chunk
    rb1 = ((bb + 1) * 66 + srow) * 1024;
  } else {
    aR0 = A + (size_t)(m0 + srow) * ldA;
    aR1 = A + (size_t)(m0 + 64 + srow) * ldA;
  }
  const u16* bR0 = Bmat + (size_t)(n0 + srow) * ldB;
  const u16* bR1 = Bmat + (size_t)(n0 + 64 + srow) * ldB;

  u16* ldsA0 = &As[tid * 8];
  u16* ldsA1 = &As[tid * 8 + 2048];
  u16* ldsB0 = &Bs[tid * 8];
  u16* ldsB1 = &Bs[tid * 8 + 2048];

  const int lane = tid & 63;
  const int warp = tid >> 6;
  const int wm = warp & 1, wn = warp >> 1;     // 2x2 wave grid
  const int l15 = lane & 15, quad = lane >> 4;

  // A frag: A[m = l15][k = quad*8 + j]; B frag: B[k = quad*8 + j][n = l15]
  const u16* aF = &As[(wm * 64 + l15) * 32 + quad * 8];
  const u16* bF = &Bs[(wn * 64 + l15) * 32 + quad * 8];

  f32x4 acc[4][4];
#pragma unroll
  for (int i = 0; i < 4; i++)
#pragma unroll
    for (int j = 0; j < 4; j++) acc[i][j] = (f32x4){0.f, 0.f, 0.f, 0.f};

  for (int k0 = 0; k0 < K; k0 += 32) {
    __syncthreads();                            // protect LDS from overwrite
    const u16 *ga0, *ga1;
    if constexpr (MODE == 1) {
      const int t = k0 >> 10;
      const int kk = (k0 & 1023) + sq;
      ga0 = A + rb0 + t * 1024 + kk;
      ga1 = A + rb1 + t * 1024 + kk;
    } else {
      ga0 = aR0 + k0 + sq;
      ga1 = aR1 + k0 + sq;
    }
    GLDS16(ga0, ldsA0);
    GLDS16(ga1, ldsA1);
    GLDS16(bR0 + k0 + sq, ldsB0);
    GLDS16(bR1 + k0 + sq, ldsB1);
    __syncthreads();                            // staging visible (implies vmcnt(0))

    short8 fa[4], fb[4];
#pragma unroll
    for (int i = 0; i < 4; i++) fa[i] = *(const short8*)(aF + i * 512);
#pragma unroll
    for (int j = 0; j < 4; j++) fb[j] = *(const short8*)(bF + j * 512);
#pragma unroll
    for (int i = 0; i < 4; i++)
#pragma unroll
      for (int j = 0; j < 4; j++)
        acc[i][j] = __builtin_amdgcn_mfma_f32_16x16x32_bf16(fa[i], fb[j], acc[i][j], 0, 0, 0);
  }

  // epilogue — C/D layout: col = l15, row = quad*4 + reg (per 16x16 frag)
  if constexpr (MODE == 0) {
    const int w = n0 >> 10;                     // which of W0/W1/W2 (uniform per block)
    const float* bp = (w == 0) ? bias0 : ((w == 1) ? bias1 : bias2);
#pragma unroll
    for (int i = 0; i < 4; i++) {
      const int mrow = m0 + wm * 64 + i * 16 + quad * 4;
#pragma unroll
      for (int j = 0; j < 4; j++) {
        const int c = n0 + wn * 64 + j * 16 + l15;
        const int n = c & 1023;
        const float bias = bp[n];
#pragma unroll
        for (int r = 0; r < 4; r++) {
          const int m = mrow + r;
          const float v = acc[i][j][r] + bias;
          if (w == 0) {
            e0bf[(size_t)m * 1024 + n] = f2bf(v);
          } else if (w == 1) {
            oute1[(size_t)m * 1024 + n] = v;
            const int bb = m >> 6, ll = m & 63;
            e1pad[(size_t)(bb * 66 + ll + 1) * 1024 + n] = f2bf(v);
          } else {
            oute2[(size_t)m * 1024 + n] = v;
            e2bf[(size_t)m * 1024 + n] = f2bf(v);
          }
        }
      }
    }
  } else {
    const float* bp = bias0;                    // folded BN bias
#pragma unroll
    for (int i = 0; i < 4; i++) {
      const int mrow = m0 + wm * 64 + i * 16 + quad * 4;
#pragma unroll
      for (int j = 0; j < 4; j++) {
        const int c = n0 + wn * 64 + j * 16 + l15;
        const float bias = bp[c];
#pragma unroll
        for (int r = 0; r < 4; r++) {
          const int m = mrow + r;
          const float v = acc[i][j][r] + bias;
          const float sg = 1.0f / (1.0f + expf(-v));
          logits[(size_t)m * NC + c] = f2bf(sg);
        }
      }
    }
  }
}

// ----------------------------------------------------- attention pooling (1 blk/b)
__global__ void attn_pool(const u16* __restrict__ e0, const float* __restrict__ w_attn,
                          const float* __restrict__ b_attn, const int* __restrict__ lens,
                          float* __restrict__ sent) {
  const int b = blockIdx.x;
  const int tid = threadIdx.x;
  const int lane = tid & 63;
  const int warp = tid >> 6;
  __shared__ float sc[64];
  __shared__ float at[64];
  const int len = lens[b];

  // scores: warp w computes l = w*16 .. w*16+15 via 64-lane dot + shuffle reduce
  for (int t = 0; t < 16; t++) {
    const int l = warp * 16 + t;
    const u16* row = e0 + (size_t)(b * 64 + l) * 1024;
    float s = 0.f;
#pragma unroll
    for (int u = 0; u < 16; u++) {
      const int d = lane + u * 64;
      s += bf2f(row[d]) * w_attn[d];
    }
#pragma unroll
    for (int off = 32; off > 0; off >>= 1) s += __shfl_down(s, off);
    if (lane == 0) sc[l] = s + b_attn[0];
  }
  __syncthreads();
  if (warp == 0) {  // masked softmax over L=64 in one wave
    float v = (lane < len) ? sc[lane] : -1e30f;
    float m = v;
#pragma unroll
    for (int off = 32; off > 0; off >>= 1) m = fmaxf(m, __shfl_xor(m, off));
    float p = (lane < len) ? expf(v - m) : 0.f;
    float ssum = p;
#pragma unroll
    for (int off = 32; off > 0; off >>= 1) ssum += __shfl_xor(ssum, off);
    at[lane] = p / ssum;
  }
  __syncthreads();
  // weighted sum over l: each thread owns 4 consecutive d
  const int d0 = tid * 4;
  float a0 = 0.f, a1 = 0.f, a2 = 0.f, a3 = 0.f;
  for (int l = 0; l < 64; l++) {
    const float wgt = at[l];
    const ushort4 u4 = *(const ushort4*)(e0 + (size_t)(b * 64 + l) * 1024 + d0);
    a0 += wgt * bf2f(u4.x);
    a1 += wgt * bf2f(u4.y);
    a2 += wgt * bf2f(u4.z);
    a3 += wgt * bf2f(u4.w);
  }
  float4 o; o.x = a0; o.y = a1; o.z = a2; o.w = a3;
  *(float4*)(sent + (size_t)b * 1024 + d0) = o;
}

// ------------------------------------------------- top-ceil(len/8) mean per (b,c)
__global__ void topk_kernel(const u16* __restrict__ logits, const int* __restrict__ lens,
                            float* __restrict__ out, int cbits) {
  const int idx = blockIdx.x * 256 + threadIdx.x;   // b*C + c
  const int C = 1 << cbits;
  const int b = idx >> cbits;
  const int c = idx & (C - 1);
  const int len = lens[b];
  const int k = (len + 7) >> 3;                     // 1..8
  const u16* base = logits + (size_t)b * 64 * C + c;
  float t[8];
#pragma unroll
  for (int j = 0; j < 8; j++) t[j] = -1e30f;
  for (int l = 0; l < 64; l++) {
    float v = (l < len) ? bf2f(base[(size_t)l * C]) : -1e30f;
#pragma unroll
    for (int j = 0; j < 8; j++) {                   // branchless sorted insert (desc)
      const float hi = fmaxf(t[j], v);
      v = fminf(t[j], v);
      t[j] = hi;
    }
  }
  float s = 0.f;
#pragma unroll
  for (int j = 0; j < 8; j++) s += (j < k) ? t[j] : 0.f;
  out[idx] = s / (float)k;
}

// --------------------------------------------------------------------- launch
extern "C" void kernel_launch(void* const* d_in, const int* in_sizes, int n_in,
                              void* d_out, int out_size, void* d_ws, size_t ws_size,
                              hipStream_t stream) {
  const float* inputs = (const float*)d_in[0];
  const int*   lens   = (const int*)d_in[1];
  const float* W0 = (const float*)d_in[2];
  const float* b0 = (const float*)d_in[3];
  const float* W1 = (const float*)d_in[4];
  const float* b1 = (const float*)d_in[5];
  const float* W2 = (const float*)d_in[6];
  const float* b2 = (const float*)d_in[7];
  const float* w_attn = (const float*)d_in[8];
  const float* b_attn = (const float*)d_in[9];
  const float* Kv   = (const float*)d_in[10];
  const float* bv   = (const float*)d_in[11];
  const float* g_v  = (const float*)d_in[12];
  const float* beta_v = (const float*)d_in[13];
  const float* mean_v = (const float*)d_in[14];
  const float* var_v  = (const float*)d_in[15];
  const float* Kn   = (const float*)d_in[16];
  const float* bn_b = (const float*)d_in[17];
  const float* g_n  = (const float*)d_in[18];
  const float* beta_n = (const float*)d_in[19];
  const float* mean_n = (const float*)d_in[20];
  const float* var_n  = (const float*)d_in[21];

  float* out = (float*)d_out;
  float* out_sent = out;                               // (128,1024)
  float* out_e1   = out + 131072;                      // (128,64,1024)
  float* out_e2   = out + 131072 + 8388608;            // (128,64,1024)
  float* out_ilv  = out + 131072 + 2 * 8388608;        // (128,512)
  float* out_iln  = out_ilv + 65536;                   // (128,1024)

  // workspace carve (~125 MB)
  char* p = (char*)d_ws;
  u16* Xbf  = (u16*)p; p += (size_t)8192 * 3072 * 2;   // inputs bf16 (reused for logits later)
  u16* Wt   = (u16*)p; p += (size_t)3072 * 3072 * 2;   // [W0|W1|W2]^T, N-major
  u16* KVt  = (u16*)p; p += (size_t)512 * 3072 * 2;    // verb weights, N-major, BN-folded
  u16* KNt  = (u16*)p; p += (size_t)1024 * 1024 * 2;   // noun weights, BN-folded
  float* biasv = (float*)p; p += 512 * 4;
  float* biasn = (float*)p; p += 1024 * 4;
  u16* e0bf  = (u16*)p; p += (size_t)8192 * 1024 * 2;
  u16* e1pad = (u16*)p; p += (size_t)128 * 66 * 1024 * 2;  // (B,66,D) zero-padded
  u16* e2bf  = (u16*)p; p += (size_t)8192 * 1024 * 2;
  u16* logv = Xbf;                                      // reuse: Xbf dead after embed GEMM
  u16* logn = Xbf + (size_t)8192 * 512;

  cast_inputs<<<24576, 256, 0, stream>>>((const float4*)inputs, (ushort4*)Xbf, 6291456);
  transpose_w<<<dim3(96, 96), dim3(32, 8), 0, stream>>>(W0, W1, W2, Wt);
  prep_kv<<<512, 256, 0, stream>>>(Kv, bv, g_v, beta_v, mean_v, var_v, KVt, biasv);
  prep_kn<<<1024, 256, 0, stream>>>(Kn, bn_b, g_n, beta_n, mean_n, var_n, KNt, biasn);
  zero_pad<<<1024, 256, 0, stream>>>(e1pad);

  gemm_tile<0><<<dim3(24, 64), 256, 0, stream>>>(Xbf, Wt, b0, b1, b2, out_e1, out_e2,
                                                 e0bf, e1pad, e2bf, nullptr);
  attn_pool<<<128, 256, 0, stream>>>(e0bf, w_attn, b_attn, lens, out_sent);
  gemm_tile<1><<<dim3(4, 64), 256, 0, stream>>>(e1pad, KVt, biasv, nullptr, nullptr,
                                                nullptr, nullptr, nullptr, nullptr,
                                                nullptr, logv);
  gemm_tile<2><<<dim3(8, 64), 256, 0, stream>>>(e2bf, KNt, biasn, nullptr, nullptr,
                                                nullptr, nullptr, nullptr, nullptr,
                                                nullptr, logn);
  topk_kernel<<<256, 256, 0, stream>>>(logv, lens, out_ilv, 9);
  topk_kernel<<<512, 256, 0, stream>>>(logn, lens, out_iln, 10);
}

// Round 3
// 515.644 us; speedup vs baseline: 1.1772x; 1.1772x over previous
//
#include <hip/hip_runtime.h>
#include <cstdint>
#include <cstddef>

// Problem constants: B=128, L=64, F=3072, D=1024, CV=512, CN=1024, MAX_K=8
typedef unsigned short u16;
typedef __attribute__((ext_vector_type(8))) short short8;   // 8 x bf16 (4 VGPRs)
typedef __attribute__((ext_vector_type(4))) float f32x4;    // MFMA accumulator

static __device__ __forceinline__ float bf2f(u16 h) {
  union { unsigned u; float f; } a; a.u = ((unsigned)h) << 16; return a.f;
}
static __device__ __forceinline__ u16 f2bf(float x) {
  union { float f; unsigned u; } a; a.f = x;
  return (u16)((a.u + 0x7fffu + ((a.u >> 16) & 1u)) >> 16);  // RNE
}

// async global->LDS, 16B per lane. LDS dest is wave-uniform base + lane*16.
#define GLDS16(gp, lp)                                                          \
  __builtin_amdgcn_global_load_lds(                                             \
      (const __attribute__((address_space(1))) void*)(gp),                      \
      (__attribute__((address_space(3))) void*)(lp), 16, 0, 0)

// ------------------------------------------------------------- merged prep
// blocks [0,24576): cast inputs fp32->bf16
// blocks [24576,33792): transpose [W0|W1|W2] -> Wt (N-major bf16)
// blocks [33792,34304): prep verb conv weights (BN folded)
// blocks [34304,35328): prep noun conv weights (BN folded)
// blocks [35328,36352): zero pad rows of e1pad
__global__ void prep_all(const float* __restrict__ inputs, u16* __restrict__ Xbf,
                         const float* __restrict__ W0, const float* __restrict__ W1,
                         const float* __restrict__ W2, u16* __restrict__ Wt,
                         const float* __restrict__ Kv, const float* __restrict__ bv,
                         const float* __restrict__ g_v, const float* __restrict__ beta_v,
                         const float* __restrict__ mean_v, const float* __restrict__ var_v,
                         u16* __restrict__ KVt, float* __restrict__ biasv,
                         const float* __restrict__ Kn, const float* __restrict__ bnb,
                         const float* __restrict__ g_n, const float* __restrict__ beta_n,
                         const float* __restrict__ mean_n, const float* __restrict__ var_n,
                         u16* __restrict__ KNt, float* __restrict__ biasn,
                         u16* __restrict__ e1pad) {
  __shared__ float tile[32][33];
  const int id = blockIdx.x;
  const int tid = threadIdx.x;
  if (id < 24576) {                       // cast: float4 -> 4x bf16
    const int i = id * 256 + tid;         // < 6291456 exactly
    float4 v = ((const float4*)inputs)[i];
    ushort4 o;
    o.x = f2bf(v.x); o.y = f2bf(v.y); o.z = f2bf(v.z); o.w = f2bf(v.w);
    ((ushort4*)Xbf)[i] = o;
  } else if (id < 33792) {                // transpose W
    const int idd = id - 24576;
    const int kb = (idd % 96) * 32;
    const int jb = (idd / 96) * 32;
    const int tx = tid & 31, ty = tid >> 5;
    const int w = jb >> 10;
    const float* W = (w == 0) ? W0 : ((w == 1) ? W1 : W2);
    const int nb = jb & 1023;
    for (int i = ty; i < 32; i += 8)
      tile[i][tx] = W[(size_t)(kb + i) * 1024 + nb + tx];
    __syncthreads();
    for (int i = ty; i < 32; i += 8)
      Wt[(size_t)(jb + i) * 3072 + kb + tx] = f2bf(tile[tx][i]);
  } else if (id < 34304) {                // prep_kv
    const int c = id - 33792;
    const float scale = g_v[c] * rsqrtf(var_v[c] + 1e-5f);
    for (int t = 0; t < 3; t++)
      for (int d = tid; d < 1024; d += 256)
        KVt[(size_t)c * 3072 + t * 1024 + d] = f2bf(Kv[(size_t)c * 3072 + d * 3 + t] * scale);
    if (tid == 0) biasv[c] = (bv[c] - mean_v[c]) * scale + beta_v[c];
  } else if (id < 35328) {                // prep_kn
    const int c = id - 34304;
    const float scale = g_n[c] * rsqrtf(var_n[c] + 1e-5f);
    for (int d = tid; d < 1024; d += 256)
      KNt[(size_t)c * 1024 + d] = f2bf(Kn[(size_t)c * 1024 + d] * scale);
    if (tid == 0) biasn[c] = (bnb[c] - mean_n[c]) * scale + beta_n[c];
  } else {                                // zero pad rows 0,65 of e1pad (B,66,D)
    const int i = (id - 35328) * 256 + tid;   // 0..262143
    const int b = i >> 11;
    const int j = i & 2047;
    const int r = (j < 1024) ? 0 : 65;
    const int d = j & 1023;
    e1pad[(size_t)(b * 66 + r) * 1024 + d] = 0;
  }
}

// ------------------------------------------------------------------ embed GEMM
// 128x128 C-tile, BK=32, 4 waves 2x2, each 64x64 via 4x4 mfma_f32_16x16x32_bf16.
// LDS XOR-swizzle: chunk for (row r, k-quad q) lives at index r*4 + ((q+(r>>1))&3)
// -> fragment ds_read_b128 phases spread over all 8 bank groups (2-way only).
__global__ void gemm_embed(const u16* __restrict__ A, const u16* __restrict__ Bmat,
                           const float* __restrict__ bias0, const float* __restrict__ bias1,
                           const float* __restrict__ bias2,
                           float* __restrict__ oute1, float* __restrict__ oute2,
                           u16* __restrict__ e0bf, u16* __restrict__ e1pad,
                           u16* __restrict__ e2bf) {
  constexpr int K = 3072;
  __shared__ __align__(16) u16 As[128 * 32];
  __shared__ __align__(16) u16 Bs[128 * 32];

  const int tid = threadIdx.x;
  const int m0 = blockIdx.y * 128;
  const int n0 = blockIdx.x * 128;

  const int srow = tid >> 2;                    // staged row (chunk tid -> srow, tid+256 -> 64+srow)
  const int qlog = ((tid & 3) - (srow >> 1)) & 3;  // swizzle: which k-quad this chunk holds
  const int sq = qlog * 8;

  const u16* aR0 = A + (size_t)(m0 + srow) * 3072;
  const u16* aR1 = A + (size_t)(m0 + 64 + srow) * 3072;
  const u16* bR0 = Bmat + (size_t)(n0 + srow) * 3072;
  const u16* bR1 = Bmat + (size_t)(n0 + 64 + srow) * 3072;

  u16* ldsA0 = &As[tid * 8];
  u16* ldsA1 = &As[tid * 8 + 2048];
  u16* ldsB0 = &Bs[tid * 8];
  u16* ldsB1 = &Bs[tid * 8 + 2048];

  const int lane = tid & 63;
  const int warp = tid >> 6;
  const int wm = warp & 1, wn = warp >> 1;
  const int l15 = lane & 15, quad = lane >> 4;
  const int swz = (quad + (l15 >> 1)) & 3;      // read-side swizzled k-quad

  const u16* aF = &As[(wm * 64 + l15) * 32 + swz * 8];
  const u16* bF = &Bs[(wn * 64 + l15) * 32 + swz * 8];

  f32x4 acc[4][4];
#pragma unroll
  for (int i = 0; i < 4; i++)
#pragma unroll
    for (int j = 0; j < 4; j++) acc[i][j] = (f32x4){0.f, 0.f, 0.f, 0.f};

  for (int k0 = 0; k0 < K; k0 += 32) {
    __syncthreads();
    GLDS16(aR0 + k0 + sq, ldsA0);
    GLDS16(aR1 + k0 + sq, ldsA1);
    GLDS16(bR0 + k0 + sq, ldsB0);
    GLDS16(bR1 + k0 + sq, ldsB1);
    __syncthreads();

    short8 fa[4], fb[4];
#pragma unroll
    for (int i = 0; i < 4; i++) fa[i] = *(const short8*)(aF + i * 512);
#pragma unroll
    for (int j = 0; j < 4; j++) fb[j] = *(const short8*)(bF + j * 512);
#pragma unroll
    for (int i = 0; i < 4; i++)
#pragma unroll
      for (int j = 0; j < 4; j++)
        acc[i][j] = __builtin_amdgcn_mfma_f32_16x16x32_bf16(fa[i], fb[j], acc[i][j], 0, 0, 0);
  }

  const int w = n0 >> 10;
  const float* bp = (w == 0) ? bias0 : ((w == 1) ? bias1 : bias2);
#pragma unroll
  for (int i = 0; i < 4; i++) {
    const int mrow = m0 + wm * 64 + i * 16 + quad * 4;
#pragma unroll
    for (int j = 0; j < 4; j++) {
      const int c = n0 + wn * 64 + j * 16 + l15;
      const int n = c & 1023;
      const float bias = bp[n];
#pragma unroll
      for (int r = 0; r < 4; r++) {
        const int m = mrow + r;
        const float v = acc[i][j][r] + bias;
        if (w == 0) {
          e0bf[(size_t)m * 1024 + n] = f2bf(v);
        } else if (w == 1) {
          oute1[(size_t)m * 1024 + n] = v;
          const int bb = m >> 6, ll = m & 63;
          e1pad[(size_t)(bb * 66 + ll + 1) * 1024 + n] = f2bf(v);
        } else {
          oute2[(size_t)m * 1024 + n] = v;
          e2bf[(size_t)m * 1024 + n] = f2bf(v);
        }
      }
    }
  }
}

// -------------------------------------------- conv GEMM + in-epilogue top-k
// MODE 1: verb (A = e1pad im2col, K=3072, NC=512); MODE 2: noun (K=1024, NC=1024).
// Each wave owns one batch (bb+wm): rows l = i*16+quad*4+r cover all 64 l for its
// 64 columns -> top-8 per column in-register, merged across quads via shfl_xor.
template<int MODE>
__device__ __forceinline__ void conv_gemm_body(
    int bx, int by, const u16* __restrict__ A, const u16* __restrict__ Bmat,
    const float* __restrict__ bias, const int* __restrict__ lens,
    float* __restrict__ out, u16* As, u16* Bs) {
  constexpr int K = (MODE == 1) ? 3072 : 1024;
  constexpr int ldB = (MODE == 1) ? 3072 : 1024;
  constexpr int NC = (MODE == 1) ? 512 : 1024;

  const int tid = threadIdx.x;
  const int m0 = by * 128;
  const int n0 = bx * 128;

  const int srow = tid >> 2;
  const int qlog = ((tid & 3) - (srow >> 1)) & 3;
  const int sq = qlog * 8;

  const u16* aR0;
  const u16* aR1;
  int rb0 = 0, rb1 = 0;
  if constexpr (MODE == 1) {
    const int bb = m0 >> 6;
    rb0 = (bb * 66 + srow) * 1024;
    rb1 = ((bb + 1) * 66 + srow) * 1024;
    aR0 = A; aR1 = A;
  } else {
    aR0 = A + (size_t)(m0 + srow) * 1024;
    aR1 = A + (size_t)(m0 + 64 + srow) * 1024;
  }
  const u16* bR0 = Bmat + (size_t)(n0 + srow) * ldB;
  const u16* bR1 = Bmat + (size_t)(n0 + 64 + srow) * ldB;

  u16* ldsA0 = &As[tid * 8];
  u16* ldsA1 = &As[tid * 8 + 2048];
  u16* ldsB0 = &Bs[tid * 8];
  u16* ldsB1 = &Bs[tid * 8 + 2048];

  const int lane = tid & 63;
  const int warp = tid >> 6;
  const int wm = warp & 1, wn = warp >> 1;
  const int l15 = lane & 15, quad = lane >> 4;
  const int swz = (quad + (l15 >> 1)) & 3;

  const u16* aF = &As[(wm * 64 + l15) * 32 + swz * 8];
  const u16* bF = &Bs[(wn * 64 + l15) * 32 + swz * 8];

  f32x4 acc[4][4];
#pragma unroll
  for (int i = 0; i < 4; i++)
#pragma unroll
    for (int j = 0; j < 4; j++) acc[i][j] = (f32x4){0.f, 0.f, 0.f, 0.f};

  for (int k0 = 0; k0 < K; k0 += 32) {
    __syncthreads();
    const u16 *ga0, *ga1;
    if constexpr (MODE == 1) {
      const int t = k0 >> 10;
      const int kk = (k0 & 1023) + sq;
      ga0 = A + rb0 + t * 1024 + kk;
      ga1 = A + rb1 + t * 1024 + kk;
    } else {
      ga0 = aR0 + k0 + sq;
      ga1 = aR1 + k0 + sq;
    }
    GLDS16(ga0, ldsA0);
    GLDS16(ga1, ldsA1);
    GLDS16(bR0 + k0 + sq, ldsB0);
    GLDS16(bR1 + k0 + sq, ldsB1);
    __syncthreads();

    short8 fa[4], fb[4];
#pragma unroll
    for (int i = 0; i < 4; i++) fa[i] = *(const short8*)(aF + i * 512);
#pragma unroll
    for (int j = 0; j < 4; j++) fb[j] = *(const short8*)(bF + j * 512);
#pragma unroll
    for (int i = 0; i < 4; i++)
#pragma unroll
      for (int j = 0; j < 4; j++)
        acc[i][j] = __builtin_amdgcn_mfma_f32_16x16x32_bf16(fa[i], fb[j], acc[i][j], 0, 0, 0);
  }

  // epilogue: sigmoid + per-column top-8 + mean of top-k
  const int b = (m0 >> 6) + wm;            // this wave's batch
  const int len = lens[b];
  const int kk8 = (len + 7) >> 3;          // k = ceil(len/8), 1..8
#pragma unroll
  for (int j = 0; j < 4; j++) {
    const int c = n0 + wn * 64 + j * 16 + l15;
    const float bias_c = bias[c];
    float t[8];
#pragma unroll
    for (int q8 = 0; q8 < 8; q8++) t[q8] = -1e30f;
#pragma unroll
    for (int i = 0; i < 4; i++) {
#pragma unroll
      for (int r = 0; r < 4; r++) {
        const int l = i * 16 + quad * 4 + r;
        const float v = acc[i][j][r] + bias_c;
        const float sg = 1.0f / (1.0f + __expf(-v));
        float x = (l < len) ? sg : -1e30f;
#pragma unroll
        for (int q8 = 0; q8 < 8; q8++) {   // branchless sorted insert (desc)
          const float hi = fmaxf(t[q8], x);
          x = fminf(t[q8], x);
          t[q8] = hi;
        }
      }
    }
    // merge top-8 lists across the 4 quads (lanes ^16, ^32).
    // SNAPSHOT the partner's entire list BEFORE inserting anything — both
    // lanes mutate t during insertion, so interleaved shfl+insert races.
#pragma unroll
    for (int mask = 16; mask <= 32; mask <<= 1) {
      float xs[8];
#pragma unroll
      for (int q8 = 0; q8 < 8; q8++) xs[q8] = __shfl_xor(t[q8], mask);
#pragma unroll
      for (int q8 = 0; q8 < 8; q8++) {
        float x = xs[q8];
#pragma unroll
        for (int p8 = 0; p8 < 8; p8++) {
          const float hi = fmaxf(t[p8], x);
          x = fminf(t[p8], x);
          t[p8] = hi;
        }
      }
    }
    if (quad == 0) {
      float s = 0.f;
#pragma unroll
      for (int q8 = 0; q8 < 8; q8++) s += (q8 < kk8) ? t[q8] : 0.f;
      out[(size_t)b * NC + c] = s / (float)kk8;
    }
  }
}

// fused tail: blocks [0,256) verb GEMM+topk; [256,768) noun GEMM+topk; [768,896) attn
__global__ void fused_tail(const u16* __restrict__ e1pad, const u16* __restrict__ KVt,
                           const float* __restrict__ biasv,
                           const u16* __restrict__ e2bf, const u16* __restrict__ KNt,
                           const float* __restrict__ biasn,
                           const u16* __restrict__ e0bf, const float* __restrict__ w_attn,
                           const float* __restrict__ b_attn, const int* __restrict__ lens,
                           float* __restrict__ out_sent, float* __restrict__ out_ilv,
                           float* __restrict__ out_iln) {
  __shared__ __align__(16) u16 smem[2 * 128 * 32 + 256];
  u16* As = smem;
  u16* Bs = smem + 128 * 32;
  const int id = blockIdx.x;
  if (id < 256) {
    conv_gemm_body<1>(id & 3, id >> 2, e1pad, KVt, biasv, lens, out_ilv, As, Bs);
  } else if (id < 768) {
    const int id2 = id - 256;
    conv_gemm_body<2>(id2 & 7, id2 >> 3, e2bf, KNt, biasn, lens, out_iln, As, Bs);
  } else {
    // ---- attention pooling, one block per batch
    const int b = id - 768;
    const int tid = threadIdx.x;
    const int lane = tid & 63;
    const int warp = tid >> 6;
    float* sc = (float*)smem;        // 64 floats
    float* at = sc + 64;             // 64 floats
    const int len = lens[b];
    for (int t = 0; t < 16; t++) {
      const int l = warp * 16 + t;
      const u16* row = e0bf + (size_t)(b * 64 + l) * 1024;
      float s = 0.f;
#pragma unroll
      for (int u = 0; u < 16; u++) {
        const int d = lane + u * 64;
        s += bf2f(row[d]) * w_attn[d];
      }
#pragma unroll
      for (int off = 32; off > 0; off >>= 1) s += __shfl_down(s, off);
      if (lane == 0) sc[l] = s + b_attn[0];
    }
    __syncthreads();
    if (warp == 0) {
      float v = (lane < len) ? sc[lane] : -1e30f;
      float m = v;
#pragma unroll
      for (int off = 32; off > 0; off >>= 1) m = fmaxf(m, __shfl_xor(m, off));
      float p = (lane < len) ? __expf(v - m) : 0.f;
      float ssum = p;
#pragma unroll
      for (int off = 32; off > 0; off >>= 1) ssum += __shfl_xor(ssum, off);
      at[lane] = p / ssum;
    }
    __syncthreads();
    const int d0 = tid * 4;
    float a0 = 0.f, a1 = 0.f, a2 = 0.f, a3 = 0.f;
    for (int l = 0; l < 64; l++) {
      const float wgt = at[l];
      const ushort4 u4 = *(const ushort4*)(e0bf + (size_t)(b * 64 + l) * 1024 + d0);
      a0 += wgt * bf2f(u4.x);
      a1 += wgt * bf2f(u4.y);
      a2 += wgt * bf2f(u4.z);
      a3 += wgt * bf2f(u4.w);
    }
    float4 o; o.x = a0; o.y = a1; o.z = a2; o.w = a3;
    *(float4*)(out_sent + (size_t)b * 1024 + d0) = o;
  }
}

// --------------------------------------------------------------------- launch
extern "C" void kernel_launch(void* const* d_in, const int* in_sizes, int n_in,
                              void* d_out, int out_size, void* d_ws, size_t ws_size,
                              hipStream_t stream) {
  const float* inputs = (const float*)d_in[0];
  const int*   lens   = (const int*)d_in[1];
  const float* W0 = (const float*)d_in[2];
  const float* b0 = (const float*)d_in[3];
  const float* W1 = (const float*)d_in[4];
  const float* b1 = (const float*)d_in[5];
  const float* W2 = (const float*)d_in[6];
  const float* b2 = (const float*)d_in[7];
  const float* w_attn = (const float*)d_in[8];
  const float* b_attn = (const float*)d_in[9];
  const float* Kv   = (const float*)d_in[10];
  const float* bv   = (const float*)d_in[11];
  const float* g_v  = (const float*)d_in[12];
  const float* beta_v = (const float*)d_in[13];
  const float* mean_v = (const float*)d_in[14];
  const float* var_v  = (const float*)d_in[15];
  const float* Kn   = (const float*)d_in[16];
  const float* bn_b = (const float*)d_in[17];
  const float* g_n  = (const float*)d_in[18];
  const float* beta_n = (const float*)d_in[19];
  const float* mean_n = (const float*)d_in[20];
  const float* var_n  = (const float*)d_in[21];

  float* out = (float*)d_out;
  float* out_sent = out;                               // (128,1024)
  float* out_e1   = out + 131072;                      // (128,64,1024)
  float* out_e2   = out + 131072 + 8388608;            // (128,64,1024)
  float* out_ilv  = out + 131072 + 2 * 8388608;        // (128,512)
  float* out_iln  = out_ilv + 65536;                   // (128,1024)

  // workspace carve
  char* p = (char*)d_ws;
  u16* Xbf  = (u16*)p; p += (size_t)8192 * 3072 * 2;   // inputs bf16
  u16* Wt   = (u16*)p; p += (size_t)3072 * 3072 * 2;   // [W0|W1|W2]^T, N-major
  u16* KVt  = (u16*)p; p += (size_t)512 * 3072 * 2;    // verb weights, BN-folded
  u16* KNt  = (u16*)p; p += (size_t)1024 * 1024 * 2;   // noun weights, BN-folded
  float* biasv = (float*)p; p += 512 * 4;
  float* biasn = (float*)p; p += 1024 * 4;
  u16* e0bf  = (u16*)p; p += (size_t)8192 * 1024 * 2;
  u16* e1pad = (u16*)p; p += (size_t)128 * 66 * 1024 * 2;  // (B,66,D) zero-padded
  u16* e2bf  = (u16*)p; p += (size_t)8192 * 1024 * 2;

  prep_all<<<36352, 256, 0, stream>>>(inputs, Xbf, W0, W1, W2, Wt,
                                      Kv, bv, g_v, beta_v, mean_v, var_v, KVt, biasv,
                                      Kn, bn_b, g_n, beta_n, mean_n, var_n, KNt, biasn,
                                      e1pad);
  gemm_embed<<<dim3(24, 64), 256, 0, stream>>>(Xbf, Wt, b0, b1, b2, out_e1, out_e2,
                                               e0bf, e1pad, e2bf);
  fused_tail<<<896, 256, 0, stream>>>(e1pad, KVt, biasv, e2bf, KNt, biasn,
                                      e0bf, w_attn, b_attn, lens,
                                      out_sent, out_ilv, out_iln);
}